// Round 5
// baseline (143.945 us; speedup 1.0000x reference)
//
#include <hip/hip_runtime.h>
#include <hip/hip_bf16.h>

#define DIM   1024
#define HEADS 16
#define B     2
#define N     2048
#define OUTER_BLOCKS 2048   // persistent grid for outer kernel

typedef float f32x4 __attribute__((ext_vector_type(4)));

// ---------------------------------------------------------------------------
// Kernel 1: logits[b,h,n] = dot(x[b,n,:], W[h,:]) + bias[h]
// One block per (b,n). 256 threads = 4 waves; each wave computes 4 heads.
// ---------------------------------------------------------------------------
__global__ __launch_bounds__(256) void logits_kernel(
    const float* __restrict__ x, const float* __restrict__ W,
    const float* __restrict__ bias, float* __restrict__ logits) {
  const int bn   = blockIdx.x;            // b*N + n
  const int tid  = threadIdx.x;
  const int wave = tid >> 6;
  const int lane = tid & 63;

  const f32x4* xrow = (const f32x4*)(x + (size_t)bn * DIM);
  f32x4 xv[4];
#pragma unroll
  for (int k = 0; k < 4; ++k) xv[k] = xrow[lane * 4 + k];

#pragma unroll
  for (int hh = 0; hh < 4; ++hh) {
    const int h = wave * 4 + hh;
    const f32x4* wrow = (const f32x4*)(W + (size_t)h * DIM);
    float s = 0.0f;
#pragma unroll
    for (int k = 0; k < 4; ++k) {
      f32x4 wv = wrow[lane * 4 + k];
      s += wv.x * xv[k].x + wv.y * xv[k].y + wv.z * xv[k].z + wv.w * xv[k].w;
    }
#pragma unroll
    for (int off = 32; off > 0; off >>= 1) s += __shfl_down(s, off, 64);
    if (lane == 0) {
      const int b = bn >> 11;   // / N
      const int n = bn & (N - 1);
      logits[((size_t)(b * HEADS + h)) * N + n] = s + bias[h];
    }
  }
}

// ---------------------------------------------------------------------------
// Kernel 2: fg[bh, :] = cumsum(logsigmoid(logits[bh, :]))
// One block per (b,h) = 32 blocks. 256 threads, 8 elements each (contiguous).
// ---------------------------------------------------------------------------
__device__ __forceinline__ float logsig(float z) {
  return fminf(z, 0.0f) - log1pf(__expf(-fabsf(z)));
}

__global__ __launch_bounds__(256) void cumsum_kernel(
    const float* __restrict__ logits, float* __restrict__ fg) {
  const int bh  = blockIdx.x;
  const int tid = threadIdx.x;
  const float* lp = logits + (size_t)bh * N;
  float*       fp = fg     + (size_t)bh * N;

  f32x4 a = ((const f32x4*)lp)[tid * 2];
  f32x4 c = ((const f32x4*)lp)[tid * 2 + 1];
  float v[8] = {a.x, a.y, a.z, a.w, c.x, c.y, c.z, c.w};

  float run = 0.0f;
#pragma unroll
  for (int i = 0; i < 8; ++i) { v[i] = logsig(v[i]); run += v[i]; v[i] = run; }
  const float total = run;

  const int lane = tid & 63, wv = tid >> 6;
  float sc = total;
#pragma unroll
  for (int off = 1; off < 64; off <<= 1) {
    float t = __shfl_up(sc, off, 64);
    if (lane >= off) sc += t;
  }

  __shared__ float wtot[4];
  if (lane == 63) wtot[wv] = sc;
  __syncthreads();
  float wofs = 0.0f;
  for (int w = 0; w < wv; ++w) wofs += wtot[w];

  const float base = wofs + sc - total;  // exclusive prefix for this thread
  f32x4 o0 = {base + v[0], base + v[1], base + v[2], base + v[3]};
  f32x4 o1 = {base + v[4], base + v[5], base + v[6], base + v[7]};
  ((f32x4*)fp)[tid * 2]     = o0;
  ((f32x4*)fp)[tid * 2 + 1] = o1;
}

// ---------------------------------------------------------------------------
// Kernel 3: out[bh, i, j] = fg[bh, i] - fg[bh, j]
// Persistent grid-stride kernel mimicking fillBuffer's structure: 2048 blocks,
// each thread does exactly 64 iterations; the whole grid advances a contiguous
// 8 MB write front per iteration. fg reads are L1/L2 hits (fg = 256 KB).
// Within a wave, `row` (and hence fi) is uniform.
// ---------------------------------------------------------------------------
__global__ __launch_bounds__(256) void outer_kernel(
    const float* __restrict__ fg, float* __restrict__ out) {
  const size_t stride = (size_t)OUTER_BLOCKS * 256;      // float4 stride per iter
  size_t idx = (size_t)blockIdx.x * 256 + threadIdx.x;   // float4 index
  f32x4* o = (f32x4*)out;
  // total float4s = B*HEADS*N*(N/4) = 33,554,432 = 64 * stride exactly
#pragma unroll 4
  for (int it = 0; it < 64; ++it, idx += stride) {
    const int row = (int)(idx >> 9);        // bh*N + i  (512 float4 per row)
    const int bh  = row >> 11;
    const int j4  = (int)(idx & 511);
    const float fi = fg[row];               // wave-uniform, L1-hit
    const f32x4 v = ((const f32x4*)(fg + ((size_t)bh << 11)))[j4];
    f32x4 r = {fi - v.x, fi - v.y, fi - v.z, fi - v.w};
    o[idx] = r;
  }
}

extern "C" void kernel_launch(void* const* d_in, const int* in_sizes, int n_in,
                              void* d_out, int out_size, void* d_ws, size_t ws_size,
                              hipStream_t stream) {
  const float* x    = (const float*)d_in[0];   // [B, N, DIM]
  const float* W    = (const float*)d_in[1];   // [HEADS, DIM]
  const float* bias = (const float*)d_in[2];   // [HEADS]
  float* out = (float*)d_out;                  // [B, HEADS, N, N]

  float* logits = (float*)d_ws;                            // B*HEADS*N f32 = 256 KB
  float* fg     = logits + (size_t)B * HEADS * N;          // B*HEADS*N f32 = 256 KB

  logits_kernel<<<B * N, 256, 0, stream>>>(x, W, bias, logits);
  cumsum_kernel<<<B * HEADS, 256, 0, stream>>>(logits, fg);
  outer_kernel<<<OUTER_BLOCKS, 256, 0, stream>>>(fg, out);
}

// Round 6
// 123.360 us; speedup vs baseline: 1.1669x; 1.1669x over previous
//
#include <hip/hip_runtime.h>
#include <hip/hip_bf16.h>

#define DIM   1024
#define HEADS 16
#define B     2
#define N     2048
#define RPW   8      // rows per wave in outer kernel

typedef float f32x4 __attribute__((ext_vector_type(4)));

// ---------------------------------------------------------------------------
// Kernel 1: logits[b,h,n] = dot(x[b,n,:], W[h,:]) + bias[h]
// One block per (b,n). 256 threads = 4 waves; each wave computes 4 heads.
// ---------------------------------------------------------------------------
__global__ __launch_bounds__(256) void logits_kernel(
    const float* __restrict__ x, const float* __restrict__ W,
    const float* __restrict__ bias, float* __restrict__ logits) {
  const int bn   = blockIdx.x;            // b*N + n
  const int tid  = threadIdx.x;
  const int wave = tid >> 6;
  const int lane = tid & 63;

  const f32x4* xrow = (const f32x4*)(x + (size_t)bn * DIM);
  f32x4 xv[4];
#pragma unroll
  for (int k = 0; k < 4; ++k) xv[k] = xrow[lane * 4 + k];

#pragma unroll
  for (int hh = 0; hh < 4; ++hh) {
    const int h = wave * 4 + hh;
    const f32x4* wrow = (const f32x4*)(W + (size_t)h * DIM);
    float s = 0.0f;
#pragma unroll
    for (int k = 0; k < 4; ++k) {
      f32x4 wv = wrow[lane * 4 + k];
      s += wv.x * xv[k].x + wv.y * xv[k].y + wv.z * xv[k].z + wv.w * xv[k].w;
    }
#pragma unroll
    for (int off = 32; off > 0; off >>= 1) s += __shfl_down(s, off, 64);
    if (lane == 0) {
      const int b = bn >> 11;   // / N
      const int n = bn & (N - 1);
      logits[((size_t)(b * HEADS + h)) * N + n] = s + bias[h];
    }
  }
}

// ---------------------------------------------------------------------------
// Kernel 2: fg[bh, :] = cumsum(logsigmoid(logits[bh, :]))
// One block per (b,h) = 32 blocks. 256 threads, 8 elements each (contiguous).
// ---------------------------------------------------------------------------
__device__ __forceinline__ float logsig(float z) {
  return fminf(z, 0.0f) - log1pf(__expf(-fabsf(z)));
}

__global__ __launch_bounds__(256) void cumsum_kernel(
    const float* __restrict__ logits, float* __restrict__ fg) {
  const int bh  = blockIdx.x;
  const int tid = threadIdx.x;
  const float* lp = logits + (size_t)bh * N;
  float*       fp = fg     + (size_t)bh * N;

  f32x4 a = ((const f32x4*)lp)[tid * 2];
  f32x4 c = ((const f32x4*)lp)[tid * 2 + 1];
  float v[8] = {a.x, a.y, a.z, a.w, c.x, c.y, c.z, c.w};

  float run = 0.0f;
#pragma unroll
  for (int i = 0; i < 8; ++i) { v[i] = logsig(v[i]); run += v[i]; v[i] = run; }
  const float total = run;

  const int lane = tid & 63, wv = tid >> 6;
  float sc = total;
#pragma unroll
  for (int off = 1; off < 64; off <<= 1) {
    float t = __shfl_up(sc, off, 64);
    if (lane >= off) sc += t;
  }

  __shared__ float wtot[4];
  if (lane == 63) wtot[wv] = sc;
  __syncthreads();
  float wofs = 0.0f;
  for (int w = 0; w < wv; ++w) wofs += wtot[w];

  const float base = wofs + sc - total;  // exclusive prefix for this thread
  f32x4 o0 = {base + v[0], base + v[1], base + v[2], base + v[3]};
  f32x4 o1 = {base + v[4], base + v[5], base + v[6], base + v[7]};
  ((f32x4*)fp)[tid * 2]     = o0;
  ((f32x4*)fp)[tid * 2 + 1] = o1;
}

// ---------------------------------------------------------------------------
// Kernel 3: out[bh, i, j] = fg[bh, i] - fg[bh, j]
// One WAVE owns 8 consecutive output rows of one (b,h). The wave preloads the
// full fj row into 32 VGPRs and the 8 fi scalars into 2 f32x4 — the steady
// state is a single contiguous 64 KB store stream per wave with ZERO loads
// (fill-kernel profile). Grid: 65536/8/4 waves = 2048 blocks.
// ---------------------------------------------------------------------------
__global__ __launch_bounds__(256) void outer_kernel(
    const float* __restrict__ fg, float* __restrict__ out) {
  const int tid  = threadIdx.x;
  const int wave = tid >> 6;
  const int lane = tid & 63;
  const int gw   = blockIdx.x * 4 + wave;     // global wave id, 0..8191
  const int row0 = gw * RPW;                  // first of 8 consecutive rows
  const int bh   = row0 >> 11;                // rows per bh = 2048, 8 | 2048
  const int i0   = row0 & (N - 1);

  const float* frow = fg + ((size_t)bh << 11);

  // full fj row in registers: lane holds f4 index lane + k*64, k = 0..7
  const f32x4* fj = (const f32x4*)frow;
  f32x4 vj[8];
#pragma unroll
  for (int k = 0; k < 8; ++k) vj[k] = fj[lane + k * 64];

  // the 8 fi scalars (same address all lanes -> broadcast loads)
  f32x4 fia = *(const f32x4*)(frow + i0);
  f32x4 fib = *(const f32x4*)(frow + i0 + 4);
  const float fi[RPW] = {fia.x, fia.y, fia.z, fia.w, fib.x, fib.y, fib.z, fib.w};

  f32x4* orow = (f32x4*)(out + ((size_t)row0 << 11));   // row0 * N
#pragma unroll
  for (int r = 0; r < RPW; ++r) {
    const float f = fi[r];
#pragma unroll
    for (int k = 0; k < 8; ++k) {
      f32x4 v = vj[k];
      f32x4 s = {f - v.x, f - v.y, f - v.z, f - v.w};
      orow[lane + k * 64] = s;
    }
    orow += N / 4;   // next row, contiguous with previous stores
  }
}

extern "C" void kernel_launch(void* const* d_in, const int* in_sizes, int n_in,
                              void* d_out, int out_size, void* d_ws, size_t ws_size,
                              hipStream_t stream) {
  const float* x    = (const float*)d_in[0];   // [B, N, DIM]
  const float* W    = (const float*)d_in[1];   // [HEADS, DIM]
  const float* bias = (const float*)d_in[2];   // [HEADS]
  float* out = (float*)d_out;                  // [B, HEADS, N, N]

  float* logits = (float*)d_ws;                            // B*HEADS*N f32 = 256 KB
  float* fg     = logits + (size_t)B * HEADS * N;          // B*HEADS*N f32 = 256 KB

  logits_kernel<<<B * N, 256, 0, stream>>>(x, W, bias, logits);
  cumsum_kernel<<<B * HEADS, 256, 0, stream>>>(logits, fg);
  outer_kernel<<<B * HEADS * N / (RPW * 4), 256, 0, stream>>>(fg, out);
}